// Round 3
// baseline (183.548 us; speedup 1.0000x reference)
//
#include <hip/hip_runtime.h>
#include <hip/hip_fp16.h>
#include <stdint.h>

// out[16384,1024] = fp16(x) @ (fp16(sparsify24(fp16(W))) * scale -> fp16) + bias
#define M_TOT 16384
#define N_TOT 1024
#define K_TOT 1024

typedef _Float16 f16x8 __attribute__((ext_vector_type(8)));
typedef float f32x4 __attribute__((ext_vector_type(4)));

// async global->LDS DMA, 16B per lane. LDS dest must be wave-uniform base + lane*16.
__device__ inline void gl2lds16(const void* g, void* l) {
    __builtin_amdgcn_global_load_lds(
        (const __attribute__((address_space(1))) void*)(uintptr_t)(g),
        (__attribute__((address_space(3))) void*)(uint32_t)(uintptr_t)(l),
        16, 0, 0);
}

// --- Kernel 1: W[K][N] fp32 -> 2:4 sparsify (fp16 domain) * scale -> wT[N][K] fp16 ---
__global__ void prep_weight(const float* __restrict__ W,
                            const float* __restrict__ scale_p,
                            _Float16* __restrict__ wT) {
    const float scale = scale_p[0];
    int idx = blockIdx.x * blockDim.x + threadIdx.x;   // K*N/4 = 262144 threads
    int k = idx & (K_TOT - 1);                         // k fastest -> coalesced wT writes
    int g = idx >> 10;                                 // group along N, 0..255
    float4 w4 = *(const float4*)&W[(size_t)k * N_TOT + g * 4];
    _Float16 h0 = (_Float16)w4.x, h1 = (_Float16)w4.y, h2 = (_Float16)w4.z, h3 = (_Float16)w4.w;
    float a0 = fabsf((float)h0), a1 = fabsf((float)h1), a2 = fabsf((float)h2), a3 = fabsf((float)h3);
    // 2nd-largest of 4 (sorted-ascending index 2); keep a >= s2 (tie semantics match ref)
    float lo01 = fminf(a0, a1), hi01 = fmaxf(a0, a1);
    float lo23 = fminf(a2, a3), hi23 = fmaxf(a2, a3);
    float s2 = fmaxf(fminf(hi01, hi23), fmaxf(lo01, lo23));
    float v0 = (a0 >= s2) ? (float)h0 : 0.0f;
    float v1 = (a1 >= s2) ? (float)h1 : 0.0f;
    float v2 = (a2 >= s2) ? (float)h2 : 0.0f;
    float v3 = (a3 >= s2) ? (float)h3 : 0.0f;
    size_t nb = (size_t)(g * 4) * K_TOT + k;
    wT[nb + 0 * K_TOT] = (_Float16)(v0 * scale);
    wT[nb + 1 * K_TOT] = (_Float16)(v1 * scale);
    wT[nb + 2 * K_TOT] = (_Float16)(v2 * scale);
    wT[nb + 3 * K_TOT] = (_Float16)(v3 * scale);
}

// --- Kernel 2: C = fp16(X) * wT^T + bias. Fused-cast, single-barrier dbuf pipeline.
// Per iter: barrier (waits tile-k DMA/ds_writes, issued one full compute phase ago)
// -> issue A(k+1) fp32 global loads + B(k+1) DMA into the OTHER buffer
// -> ds_read frags(k) -> 16 MFMA -> cvt+ds_write A(k+1).
// The barrier's forced vmcnt(0) therefore only drains loads that have been in
// flight for ~a full compute phase, instead of stalling cold each iteration.
__global__ void __launch_bounds__(256) gemm_fused(const float* __restrict__ X,
                                                  const _Float16* __restrict__ Bt,
                                                  const float* __restrict__ bias,
                                                  float* __restrict__ C) {
    __shared__ _Float16 sA[2][128 * 32];
    __shared__ _Float16 sB[2][128 * 32];
    const int tid = threadIdx.x;
    const int id = blockIdx.x;
    const int by = id & 127;            // M tile (fastest -> by%8 = XCD; A-tile shared per XCD)
    const int bx = id >> 7;             // N tile: 0..7
    const int wave = tid >> 6;
    const int lane = tid & 63;
    const int wm = wave >> 1, wn = wave & 1;
    const int quad = lane >> 4;
    const int l16 = lane & 15;

    // A staging: thread t handles row (t>>1), 16 consecutive fp32 at col (t&1)*16
    const int arow = tid >> 1;
    const int acol = (tid & 1) * 16;
    const float* gA = X + ((size_t)(by * 128 + arow)) * K_TOT + acol;
    const int aoff = arow * 32 + acol;          // element offset in sA tile

    // B staging via DMA: thread t -> row (t>>2), 8 fp16 at col (t&3)*8 (lane-contiguous x16B)
    const int srow = tid >> 2;
    const int scol = (tid & 3) * 8;
    const _Float16* gB = Bt + ((size_t)(bx * 128 + srow)) * K_TOT + scol;
    const int boff = srow * 32 + scol;

    f32x4 acc[4][4];
#pragma unroll
    for (int i = 0; i < 4; ++i)
#pragma unroll
        for (int j = 0; j < 4; ++j)
            acc[i][j] = (f32x4){0.f, 0.f, 0.f, 0.f};

    // ---- prologue: stage tile 0 into buffer 0 ----
    {
        float4 a0 = *(const float4*)(gA + 0);
        float4 a1 = *(const float4*)(gA + 4);
        float4 a2 = *(const float4*)(gA + 8);
        float4 a3 = *(const float4*)(gA + 12);
        gl2lds16(gB, &sB[0][boff]);
        gl2lds16(gB + (size_t)64 * K_TOT, &sB[0][boff + 64 * 32]);
        f16x8 h0, h1;
        h0[0] = (_Float16)a0.x; h0[1] = (_Float16)a0.y; h0[2] = (_Float16)a0.z; h0[3] = (_Float16)a0.w;
        h0[4] = (_Float16)a1.x; h0[5] = (_Float16)a1.y; h0[6] = (_Float16)a1.z; h0[7] = (_Float16)a1.w;
        h1[0] = (_Float16)a2.x; h1[1] = (_Float16)a2.y; h1[2] = (_Float16)a2.z; h1[3] = (_Float16)a2.w;
        h1[4] = (_Float16)a3.x; h1[5] = (_Float16)a3.y; h1[6] = (_Float16)a3.z; h1[7] = (_Float16)a3.w;
        *(f16x8*)&sA[0][aoff] = h0;
        *(f16x8*)&sA[0][aoff + 8] = h1;
    }

#pragma unroll 2
    for (int k0 = 0; k0 < K_TOT; k0 += 32) {
        const int cur = (k0 >> 5) & 1;
        const int nxt = cur ^ 1;
        __syncthreads();   // waits tile-k ds_writes (lgkm) + tile-k B DMA (vmcnt)

        // prefetch tile k+1 (issued AFTER the barrier so this iteration's barrier
        // never waited on it; clamp to 0 on last iter — harmless re-read)
        const int kn = (k0 + 32 < K_TOT) ? (k0 + 32) : 0;
        float4 a0 = *(const float4*)(gA + kn);
        float4 a1 = *(const float4*)(gA + kn + 4);
        float4 a2 = *(const float4*)(gA + kn + 8);
        float4 a3 = *(const float4*)(gA + kn + 12);
        gl2lds16(gB + kn, &sB[nxt][boff]);
        gl2lds16(gB + kn + (size_t)64 * K_TOT, &sB[nxt][boff + 64 * 32]);

        // compute on tile k
        f16x8 af[4], bf[4];
#pragma unroll
        for (int i = 0; i < 4; ++i) {
            af[i] = *(const f16x8*)&sA[cur][(wm * 64 + i * 16 + l16) * 32 + quad * 8];
            bf[i] = *(const f16x8*)&sB[cur][(wn * 64 + i * 16 + l16) * 32 + quad * 8];
        }
#pragma unroll
        for (int i = 0; i < 4; ++i)
#pragma unroll
            for (int j = 0; j < 4; ++j)
                acc[i][j] = __builtin_amdgcn_mfma_f32_16x16x32_f16(af[i], bf[j], acc[i][j], 0, 0, 0);

        // cvt (RNE, matches jnp astype) + stage A(k+1); vmcnt wait here only
        // covers the fp32 loads, which had the whole MFMA phase in flight
        f16x8 h0, h1;
        h0[0] = (_Float16)a0.x; h0[1] = (_Float16)a0.y; h0[2] = (_Float16)a0.z; h0[3] = (_Float16)a0.w;
        h0[4] = (_Float16)a1.x; h0[5] = (_Float16)a1.y; h0[6] = (_Float16)a1.z; h0[7] = (_Float16)a1.w;
        h1[0] = (_Float16)a2.x; h1[1] = (_Float16)a2.y; h1[2] = (_Float16)a2.z; h1[3] = (_Float16)a2.w;
        h1[4] = (_Float16)a3.x; h1[5] = (_Float16)a3.y; h1[6] = (_Float16)a3.z; h1[7] = (_Float16)a3.w;
        *(f16x8*)&sA[nxt][aoff] = h0;
        *(f16x8*)&sA[nxt][aoff + 8] = h1;
    }

    // epilogue: D row = quad*4 + r, col = l16 per 16x16 tile; bias add, plain stores
#pragma unroll
    for (int j = 0; j < 4; ++j) {
        const int col = bx * 128 + wn * 64 + j * 16 + l16;
        const float bj = bias[col];
#pragma unroll
        for (int i = 0; i < 4; ++i) {
            const int row0 = by * 128 + wm * 64 + i * 16 + quad * 4;
#pragma unroll
            for (int r = 0; r < 4; ++r) {
                C[(size_t)(row0 + r) * N_TOT + col] = acc[i][j][r] + bj;
            }
        }
    }
}

extern "C" void kernel_launch(void* const* d_in, const int* in_sizes, int n_in,
                              void* d_out, int out_size, void* d_ws, size_t ws_size,
                              hipStream_t stream) {
    const float* x      = (const float*)d_in[0];   // [4,4096,1024] fp32
    const float* weight = (const float*)d_in[1];   // [1024,1024] fp32
    const float* bias   = (const float*)d_in[2];   // [1024] fp32
    const float* sscale = (const float*)d_in[3];   // [1] fp32
    float* out = (float*)d_out;

    _Float16* wT = (_Float16*)d_ws;                // 2 MiB

    prep_weight<<<(K_TOT * N_TOT / 4) / 256, 256, 0, stream>>>(weight, sscale, wT);
    gemm_fused<<<1024, 256, 0, stream>>>(x, wT, bias, out);
}

// Round 4
// 160.324 us; speedup vs baseline: 1.1449x; 1.1449x over previous
//
#include <hip/hip_runtime.h>
#include <hip/hip_fp16.h>
#include <stdint.h>

// out[16384,1024] = fp16(x) @ (fp16(sparsify24(fp16(W))) * scale -> fp16) + bias
#define M_TOT 16384
#define N_TOT 1024
#define K_TOT 1024

typedef _Float16 f16x8 __attribute__((ext_vector_type(8)));
typedef float f32x4 __attribute__((ext_vector_type(4)));
typedef unsigned short ushort4v __attribute__((ext_vector_type(4)));

// async global->LDS DMA, 16B per lane. LDS dest must be wave-uniform base + lane*16.
__device__ inline void gl2lds16(const void* g, void* l) {
    __builtin_amdgcn_global_load_lds(
        (const __attribute__((address_space(1))) void*)(uintptr_t)(g),
        (__attribute__((address_space(3))) void*)(uint32_t)(uintptr_t)(l),
        16, 0, 0);
}

// --- Kernel 1: W[K][N] fp32 -> 2:4 sparsify (fp16 domain) * scale -> wT[N][K] fp16 ---
// Coalesced both sides via 64x64 LDS transpose tile (old version read W at 4KB
// lane stride -> latency-bound scattered reads).
__global__ void __launch_bounds__(256) prep_weight(const float* __restrict__ W,
                                                   const float* __restrict__ scale_p,
                                                   _Float16* __restrict__ wT) {
    __shared__ _Float16 sT[64 * 68 + 4];   // sT[n][k], stride 68 (pad) — n,k local
    const float scale = scale_p[0];
    const int k0 = (blockIdx.x & 15) * 64;
    const int n0 = (blockIdx.x >> 4) * 64;
    const int tid = threadIdx.x;
    const int r = tid >> 4;            // 0..15
    const int c4 = (tid & 15) * 4;     // 0..60, the 2:4 group = one float4
#pragma unroll
    for (int p = 0; p < 4; ++p) {
        const int k = p * 16 + r;      // local k row
        float4 w4 = *(const float4*)&W[(size_t)(k0 + k) * N_TOT + n0 + c4];
        _Float16 h0 = (_Float16)w4.x, h1 = (_Float16)w4.y, h2 = (_Float16)w4.z, h3 = (_Float16)w4.w;
        float a0 = fabsf((float)h0), a1 = fabsf((float)h1), a2 = fabsf((float)h2), a3 = fabsf((float)h3);
        // 2nd-largest of 4; keep a >= s2 (tie semantics match ref's a >= sorted[2])
        float lo01 = fminf(a0, a1), hi01 = fmaxf(a0, a1);
        float lo23 = fminf(a2, a3), hi23 = fmaxf(a2, a3);
        float s2 = fmaxf(fminf(hi01, hi23), fmaxf(lo01, lo23));
        sT[(c4 + 0) * 68 + k] = (_Float16)(((a0 >= s2) ? (float)h0 : 0.0f) * scale);
        sT[(c4 + 1) * 68 + k] = (_Float16)(((a1 >= s2) ? (float)h1 : 0.0f) * scale);
        sT[(c4 + 2) * 68 + k] = (_Float16)(((a2 >= s2) ? (float)h2 : 0.0f) * scale);
        sT[(c4 + 3) * 68 + k] = (_Float16)(((a3 >= s2) ? (float)h3 : 0.0f) * scale);
    }
    __syncthreads();
#pragma unroll
    for (int p = 0; p < 4; ++p) {
        const int n = p * 16 + r;      // local n row of wT
        // 4 consecutive k per thread, 8B aligned (68*2=136 %8==0, c4*2 %8==0)
        ushort4v v = *(const ushort4v*)&sT[n * 68 + c4];
        *(ushort4v*)&wT[(size_t)(n0 + n) * K_TOT + k0 + c4] = v;
    }
}

// --- Kernel 2: x fp32 -> fp16 (pure stream; leaves xh hot in L3 for the GEMM) ---
__global__ void cast_x(const float* __restrict__ X, _Float16* __restrict__ Xh) {
    size_t i = ((size_t)blockIdx.x * blockDim.x + threadIdx.x) * 8;
    float4 x0 = *(const float4*)&X[i];
    float4 x1 = *(const float4*)&X[i + 4];
    f16x8 h;
    h[0] = (_Float16)x0.x; h[1] = (_Float16)x0.y; h[2] = (_Float16)x0.z; h[3] = (_Float16)x0.w;
    h[4] = (_Float16)x1.x; h[5] = (_Float16)x1.y; h[6] = (_Float16)x1.z; h[7] = (_Float16)x1.w;
    *(f16x8*)&Xh[i] = h;
}

// --- Kernel 3: C = A[M][K] * wT[N][K]^T + bias, 128x128 tile.
// Two BK=32 sub-tiles staged per barrier phase (effective BK=64): halves the
// number of vmcnt(0)+barrier stalls and doubles MFMA work per phase (32/wave),
// while keeping the proven 64B-row-stride LDS layout (2-way bank alias = free;
// a true BK=64 row layout would be 128B stride -> 16-lane same-bank frag reads).
// 1D grid swizzled so the 8 blocks sharing an A-tile land on one XCD
// (xcd = id%8 = by%8): per-XCD unique A = 4 MB fp16 -> fits 4 MiB L2.
__global__ void __launch_bounds__(256) gemm_bt(const _Float16* __restrict__ A,
                                               const _Float16* __restrict__ Bt,
                                               const float* __restrict__ bias,
                                               float* __restrict__ C) {
    __shared__ _Float16 sA[2][128 * 32];   // [sub-tile s][row][k'] — NOT double-buffer
    __shared__ _Float16 sB[2][128 * 32];
    const int tid = threadIdx.x;
    const int id = blockIdx.x;
    const int by = id & 127;            // M tile (fastest -> by%8 selects XCD)
    const int bx = id >> 7;             // N tile: 0..7
    const int wave = tid >> 6;
    const int lane = tid & 63;
    const int wm = wave >> 1, wn = wave & 1;
    const int quad = lane >> 4;
    const int l16 = lane & 15;

    const int srow = tid >> 2;          // 0..63
    const int scol = (tid & 3) * 8;     // 0,8,16,24

    const _Float16* gA = A + ((size_t)(by * 128 + srow)) * K_TOT + scol;
    const _Float16* gB = Bt + ((size_t)(bx * 128 + srow)) * K_TOT + scol;
    const int soff = srow * 32 + scol;  // byte offset == tid*16 (lane-contiguous, DMA-legal)

    f32x4 acc[4][4];
#pragma unroll
    for (int i = 0; i < 4; ++i)
#pragma unroll
        for (int j = 0; j < 4; ++j)
            acc[i][j] = (f32x4){0.f, 0.f, 0.f, 0.f};

    for (int k0 = 0; k0 < K_TOT; k0 += 64) {
        __syncthreads();                 // prior phase's ds_reads complete; LDS reusable
        gl2lds16(gA + k0,                         &sA[0][soff]);
        gl2lds16(gA + k0 + (size_t)64 * K_TOT,    &sA[0][soff + 64 * 32]);
        gl2lds16(gA + k0 + 32,                    &sA[1][soff]);
        gl2lds16(gA + k0 + 32 + (size_t)64 * K_TOT, &sA[1][soff + 64 * 32]);
        gl2lds16(gB + k0,                         &sB[0][soff]);
        gl2lds16(gB + k0 + (size_t)64 * K_TOT,    &sB[0][soff + 64 * 32]);
        gl2lds16(gB + k0 + 32,                    &sB[1][soff]);
        gl2lds16(gB + k0 + 32 + (size_t)64 * K_TOT, &sB[1][soff + 64 * 32]);
        __syncthreads();                 // single vmcnt(0) drain covers BOTH sub-tiles

#pragma unroll
        for (int s = 0; s < 2; ++s) {
            f16x8 af[4], bf[4];
#pragma unroll
            for (int i = 0; i < 4; ++i) {
                af[i] = *(const f16x8*)&sA[s][(wm * 64 + i * 16 + l16) * 32 + quad * 8];
                bf[i] = *(const f16x8*)&sB[s][(wn * 64 + i * 16 + l16) * 32 + quad * 8];
            }
#pragma unroll
            for (int i = 0; i < 4; ++i)
#pragma unroll
                for (int j = 0; j < 4; ++j)
                    acc[i][j] = __builtin_amdgcn_mfma_f32_16x16x32_f16(af[i], bf[j], acc[i][j], 0, 0, 0);
        }
    }

    // epilogue: D row = quad*4 + r, col = l16 per 16x16 tile; bias add, plain stores
#pragma unroll
    for (int j = 0; j < 4; ++j) {
        const int col = bx * 128 + wn * 64 + j * 16 + l16;
        const float bj = bias[col];
#pragma unroll
        for (int i = 0; i < 4; ++i) {
            const int row0 = by * 128 + wm * 64 + i * 16 + quad * 4;
#pragma unroll
            for (int r = 0; r < 4; ++r) {
                C[(size_t)(row0 + r) * N_TOT + col] = acc[i][j][r] + bj;
            }
        }
    }
}

extern "C" void kernel_launch(void* const* d_in, const int* in_sizes, int n_in,
                              void* d_out, int out_size, void* d_ws, size_t ws_size,
                              hipStream_t stream) {
    const float* x      = (const float*)d_in[0];   // [4,4096,1024] fp32
    const float* weight = (const float*)d_in[1];   // [1024,1024] fp32
    const float* bias   = (const float*)d_in[2];   // [1024] fp32
    const float* sscale = (const float*)d_in[3];   // [1] fp32
    float* out = (float*)d_out;

    _Float16* wT = (_Float16*)d_ws;                                    // 2 MiB
    _Float16* xh = (_Float16*)((char*)d_ws + (size_t)2 * 1024 * 1024); // 32 MiB

    prep_weight<<<256, 256, 0, stream>>>(weight, sscale, wT);
    cast_x<<<(M_TOT * K_TOT / 8) / 256, 256, 0, stream>>>(x, xh);
    gemm_bt<<<1024, 256, 0, stream>>>(xh, wT, bias, out);
}

// Round 5
// 149.542 us; speedup vs baseline: 1.2274x; 1.0721x over previous
//
#include <hip/hip_runtime.h>
#include <hip/hip_fp16.h>
#include <stdint.h>

// out[16384,1024] = fp16(x) @ (fp16(sparsify24(fp16(W))) * scale -> fp16) + bias
#define M_TOT 16384
#define N_TOT 1024
#define K_TOT 1024

typedef _Float16 f16x8 __attribute__((ext_vector_type(8)));
typedef float f32x4 __attribute__((ext_vector_type(4)));
typedef unsigned short ushort4v __attribute__((ext_vector_type(4)));

// async global->LDS DMA, 16B per lane. LDS dest must be wave-uniform base + lane*16.
__device__ inline void gl2lds16(const void* g, void* l) {
    __builtin_amdgcn_global_load_lds(
        (const __attribute__((address_space(1))) void*)(uintptr_t)(g),
        (__attribute__((address_space(3))) void*)(uint32_t)(uintptr_t)(l),
        16, 0, 0);
}

// --- Kernel 1 (fused): blocks [0,256) do weight prep; blocks [256, 256+8192) cast x.
// Block-uniform branch, no divergence; saves one graph node of launch overhead.
__global__ void __launch_bounds__(256) prep_and_cast(const float* __restrict__ X,
                                                     const float* __restrict__ W,
                                                     const float* __restrict__ scale_p,
                                                     _Float16* __restrict__ Xh,
                                                     _Float16* __restrict__ wT) {
    const int tid = threadIdx.x;
    if (blockIdx.x < 256) {
        // W[K][N] fp32 -> fp16 -> 2:4 sparsify along N (groups of 4) * scale -> wT[N][K] fp16
        __shared__ _Float16 sT[64 * 68 + 4];   // sT[n][k], stride 68 (pad)
        const float scale = scale_p[0];
        const int k0 = (blockIdx.x & 15) * 64;
        const int n0 = (blockIdx.x >> 4) * 64;
        const int r = tid >> 4;            // 0..15
        const int c4 = (tid & 15) * 4;     // 0..60: one 2:4 group = one float4
#pragma unroll
        for (int p = 0; p < 4; ++p) {
            const int k = p * 16 + r;
            float4 w4 = *(const float4*)&W[(size_t)(k0 + k) * N_TOT + n0 + c4];
            _Float16 h0 = (_Float16)w4.x, h1 = (_Float16)w4.y, h2 = (_Float16)w4.z, h3 = (_Float16)w4.w;
            float a0 = fabsf((float)h0), a1 = fabsf((float)h1), a2 = fabsf((float)h2), a3 = fabsf((float)h3);
            // 2nd-largest of 4; keep a >= s2 (matches ref's a >= sorted[2] tie semantics)
            float lo01 = fminf(a0, a1), hi01 = fmaxf(a0, a1);
            float lo23 = fminf(a2, a3), hi23 = fmaxf(a2, a3);
            float s2 = fmaxf(fminf(hi01, hi23), fmaxf(lo01, lo23));
            sT[(c4 + 0) * 68 + k] = (_Float16)(((a0 >= s2) ? (float)h0 : 0.0f) * scale);
            sT[(c4 + 1) * 68 + k] = (_Float16)(((a1 >= s2) ? (float)h1 : 0.0f) * scale);
            sT[(c4 + 2) * 68 + k] = (_Float16)(((a2 >= s2) ? (float)h2 : 0.0f) * scale);
            sT[(c4 + 3) * 68 + k] = (_Float16)(((a3 >= s2) ? (float)h3 : 0.0f) * scale);
        }
        __syncthreads();
#pragma unroll
        for (int p = 0; p < 4; ++p) {
            const int n = p * 16 + r;
            ushort4v v = *(const ushort4v*)&sT[n * 68 + c4];   // 8B aligned
            *(ushort4v*)&wT[(size_t)(n0 + n) * K_TOT + k0 + c4] = v;
        }
    } else {
        // x fp32 -> fp16 stream (leaves xh hot in L3 for the GEMM)
        size_t i = ((size_t)(blockIdx.x - 256) * 256 + tid) * 8;
        float4 x0 = *(const float4*)&X[i];
        float4 x1 = *(const float4*)&X[i + 4];
        f16x8 h;
        h[0] = (_Float16)x0.x; h[1] = (_Float16)x0.y; h[2] = (_Float16)x0.z; h[3] = (_Float16)x0.w;
        h[4] = (_Float16)x1.x; h[5] = (_Float16)x1.y; h[6] = (_Float16)x1.z; h[7] = (_Float16)x1.w;
        *(f16x8*)&Xh[i] = h;
    }
}

// --- Kernel 2: C = A[M][K] * wT[N][K]^T + bias. 256x128 tile, 512 threads (8 waves),
// BK=64 as two BK=32 sub-tiles per barrier phase. vs r4's 128x128: 1.33x more MFMA
// per staged byte (256 MFMA / 48 KB vs 128 / 32 KB) and half the barrier-drain
// phases per CU (2 blocks x 16 phases vs 4 x 16), same 16 waves/CU.
// Keeps the proven 64B-row-stride LDS layout (dense wave-wide b128 sweeps).
// 1D grid swizzled: by = id & 63 -> xcd = id % 8 = by % 8, so the 8 blocks sharing
// an A-tile land on one XCD; per-XCD unique A = 8 x 512 KB = 4 MB -> fits 4 MiB L2.
__global__ void __launch_bounds__(512) gemm_bt(const _Float16* __restrict__ A,
                                               const _Float16* __restrict__ Bt,
                                               const float* __restrict__ bias,
                                               float* __restrict__ C) {
    __shared__ _Float16 sA[2][256 * 32];   // [sub-tile s][row][k']
    __shared__ _Float16 sB[2][128 * 32];
    const int tid = threadIdx.x;
    const int id = blockIdx.x;
    const int by = id & 63;             // M tile: 0..63 (fastest -> by%8 selects XCD)
    const int bx = id >> 6;             // N tile: 0..7
    const int wave = tid >> 6;          // 0..7
    const int lane = tid & 63;
    const int wm = wave >> 1;           // 0..3 -> M sub-block
    const int wn = wave & 1;            // 0..1 -> N sub-block
    const int quad = lane >> 4;
    const int l16 = lane & 15;

    const int srow = tid >> 2;          // 0..127
    const int scol = (tid & 3) * 8;     // 0,8,16,24

    const _Float16* gA = A + ((size_t)(by * 256 + srow)) * K_TOT + scol;
    const _Float16* gB = Bt + ((size_t)(bx * 128 + srow)) * K_TOT + scol;
    const int soff = srow * 32 + scol;  // byte offset == tid*16 (lane-contiguous, DMA-legal)

    f32x4 acc[4][4];
#pragma unroll
    for (int i = 0; i < 4; ++i)
#pragma unroll
        for (int j = 0; j < 4; ++j)
            acc[i][j] = (f32x4){0.f, 0.f, 0.f, 0.f};

    for (int k0 = 0; k0 < K_TOT; k0 += 64) {
        __syncthreads();                 // prior phase's ds_reads complete; LDS reusable
        gl2lds16(gA + k0,                            &sA[0][soff]);
        gl2lds16(gA + k0 + (size_t)128 * K_TOT,      &sA[0][soff + 128 * 32]);
        gl2lds16(gA + k0 + 32,                       &sA[1][soff]);
        gl2lds16(gA + k0 + 32 + (size_t)128 * K_TOT, &sA[1][soff + 128 * 32]);
        gl2lds16(gB + k0,                            &sB[0][soff]);
        gl2lds16(gB + k0 + 32,                       &sB[1][soff]);
        __syncthreads();                 // single vmcnt(0) drain covers both sub-tiles

#pragma unroll
        for (int s = 0; s < 2; ++s) {
            f16x8 af[4], bf[4];
#pragma unroll
            for (int i = 0; i < 4; ++i) {
                af[i] = *(const f16x8*)&sA[s][(wm * 64 + i * 16 + l16) * 32 + quad * 8];
                bf[i] = *(const f16x8*)&sB[s][(wn * 64 + i * 16 + l16) * 32 + quad * 8];
            }
#pragma unroll
            for (int i = 0; i < 4; ++i)
#pragma unroll
                for (int j = 0; j < 4; ++j)
                    acc[i][j] = __builtin_amdgcn_mfma_f32_16x16x32_f16(af[i], bf[j], acc[i][j], 0, 0, 0);
        }
    }

    // epilogue: D row = quad*4 + r, col = l16 per 16x16 tile; bias add, plain stores
#pragma unroll
    for (int j = 0; j < 4; ++j) {
        const int col = bx * 128 + wn * 64 + j * 16 + l16;
        const float bj = bias[col];
#pragma unroll
        for (int i = 0; i < 4; ++i) {
            const int row0 = by * 256 + wm * 64 + i * 16 + quad * 4;
#pragma unroll
            for (int r = 0; r < 4; ++r) {
                C[(size_t)(row0 + r) * N_TOT + col] = acc[i][j][r] + bj;
            }
        }
    }
}

extern "C" void kernel_launch(void* const* d_in, const int* in_sizes, int n_in,
                              void* d_out, int out_size, void* d_ws, size_t ws_size,
                              hipStream_t stream) {
    const float* x      = (const float*)d_in[0];   // [4,4096,1024] fp32
    const float* weight = (const float*)d_in[1];   // [1024,1024] fp32
    const float* bias   = (const float*)d_in[2];   // [1024] fp32
    const float* sscale = (const float*)d_in[3];   // [1] fp32
    float* out = (float*)d_out;

    _Float16* wT = (_Float16*)d_ws;                                    // 2 MiB
    _Float16* xh = (_Float16*)((char*)d_ws + (size_t)2 * 1024 * 1024); // 32 MiB

    prep_and_cast<<<256 + (M_TOT * K_TOT / 8) / 256, 256, 0, stream>>>(x, weight, sscale, xh, wT);
    gemm_bt<<<512, 512, 0, stream>>>(xh, wT, bias, out);
}